// Round 2
// baseline (9223.755 us; speedup 1.0000x reference)
//
#include <hip/hip_runtime.h>
#include <hip/hip_bf16.h>

#define BATCH 1024
#define TSEQ  2048
#define DIN   15
#define DINP  16    // padded x row in LDS
#define HID   64
#define NG    256   // 4*HID gates
#define NT    512   // threads: 2 per gate (split-K halves)
#define CHUNK 64    // timesteps of x staged in LDS per load
#define NCLS  4

__device__ __forceinline__ float rcp_f(float x) { return __builtin_amdgcn_rcpf(x); }
__device__ __forceinline__ float sigm_f(float z) { return rcp_f(1.0f + __expf(-z)); }
__device__ __forceinline__ float tanh_f(float z) { return 1.0f - 2.0f * rcp_f(1.0f + __expf(2.0f * z)); }

// One block per batch element. 512 threads: thread t owns gate g = t>>1,
// K-half h = t&1. Per-thread weights: 8 (x) + 32 (whh0) + 64 ([wih1|whh1])
// = 104 floats -> fits registers under __launch_bounds__(512,4) (VGPR<=128),
// unlike the 208/thread of the previous version which spilled.
// Partial sums combine via __shfl_xor(.,1) (adjacent lanes, quad-perm DPP).
// Gate order (PyTorch): [0,64)=i [64,128)=f [128,192)=g(tanh) [192,256)=o.
// 32 gates per wave -> activation select wave-uniform.
__global__ __launch_bounds__(NT, 4)
void lstm2_fused(const float* __restrict__ x,
                 const float* __restrict__ wih0, const float* __restrict__ whh0,
                 const float* __restrict__ bih0, const float* __restrict__ bhh0,
                 const float* __restrict__ wih1, const float* __restrict__ whh1,
                 const float* __restrict__ bih1, const float* __restrict__ bhh1,
                 const float* __restrict__ fcw,  const float* __restrict__ fcb,
                 float* __restrict__ out)
{
    const int b  = blockIdx.x;
    const int t0 = threadIdx.x;
    const int g  = t0 >> 1;   // gate 0..255
    const int h  = t0 & 1;    // K-half
    const int wv = t0 >> 6;   // wave id 0..7
    const int ln = t0 & 63;   // lane in wave

    // ---- register-resident weight slices -----------------------------------
    float rwx[8];      // wih0[g][8h : 8h+8]  (padded with 0 past DIN)
    float rh0[32];     // whh0[g][32h : 32h+32]
    float rc1[64];     // h==0: wih1[g][:]   h==1: whh1[g][:]
    {
        const float* p = wih0 + g * DIN + 8 * h;
        #pragma unroll
        for (int j = 0; j < 8; ++j) rwx[j] = (8 * h + j < DIN) ? p[j] : 0.0f;

        const float4* q0 = (const float4*)(whh0 + g * HID + 32 * h);
        #pragma unroll
        for (int k = 0; k < 8; ++k) ((float4*)rh0)[k] = q0[k];

        const float* src1 = h ? (whh1 + g * HID) : (wih1 + g * HID);
        const float4* q1 = (const float4*)src1;
        #pragma unroll
        for (int k = 0; k < 16; ++k) ((float4*)rc1)[k] = q1[k];
    }
    const float pb0 = (h == 0) ? (bih0[g] + bhh0[g]) : 0.0f;
    const float pb1 = (h == 0) ? (bih1[g] + bhh1[g]) : 0.0f;

    // ---- LDS ----------------------------------------------------------------
    __shared__ __align__(16) float shc[2 * HID];      // [h0 | h1]
    __shared__ __align__(16) float sg0[NG];           // layer-0 activated gates
    __shared__ __align__(16) float sg1[NG];           // layer-1 activated gates
    __shared__ __align__(16) float sx[CHUNK * DINP];  // x chunk, padded rows

    if (t0 < 2 * HID) shc[t0] = 0.0f;   // h0 = h1 = 0

    float cst = 0.0f;   // c0 state for wave 0 lanes, c1 state for wave 1 lanes

    const float* xb = x + (size_t)b * TSEQ * DIN;

    for (int t = 0; t < TSEQ; ++t) {
        // ---- stage next CHUNK timesteps of x (prior sx readers are behind
        // barrier b1 of step t-1; initial shc zeroing covered by this barrier)
        if ((t & (CHUNK - 1)) == 0) {
            for (int idx = t0; idx < CHUNK * DIN; idx += NT) {
                int s = idx / DIN;
                int d = idx - s * DIN;
                sx[s * DINP + d] = xb[(size_t)t * DIN + idx];
            }
            if (t0 < CHUNK) sx[t0 * DINP + DIN] = 0.0f;  // zero the pad lane
            __syncthreads();
        }

        // ---- layer 0, half-dot: pb0 + x_t[8h:8h+8].rwx + h0[32h:32h+32].rh0
        const float4* xs4 = (const float4*)(sx + (t & (CHUNK - 1)) * DINP + 8 * h);
        float a0 = pb0, a1 = 0.0f, a2 = 0.0f, a3 = 0.0f;
        #pragma unroll
        for (int k = 0; k < 2; ++k) {
            float4 v = xs4[k];
            a0 += v.x * rwx[4 * k + 0];
            a1 += v.y * rwx[4 * k + 1];
            a2 += v.z * rwx[4 * k + 2];
            a3 += v.w * rwx[4 * k + 3];
        }
        const float4* h4 = (const float4*)(shc + 32 * h);
        #pragma unroll
        for (int k = 0; k < 8; ++k) {
            float4 v = h4[k];
            a0 += v.x * rh0[4 * k + 0];
            a1 += v.y * rh0[4 * k + 1];
            a2 += v.z * rh0[4 * k + 2];
            a3 += v.w * rh0[4 * k + 3];
        }
        float zp = (a0 + a1) + (a2 + a3);
        float z0 = zp + __shfl_xor(zp, 1);            // combine halves (in-wave)
        float av0 = ((g >> 6) == 2) ? tanh_f(z0) : sigm_f(z0);
        if (h == 0) sg0[g] = av0;
        __syncthreads();                               // b1

        if (wv == 0) {  // wave 0: update c0, h0 (lane ln <-> hidden dim ln)
            float iv = sg0[ln], fv = sg0[64 + ln], gv = sg0[128 + ln], ov = sg0[192 + ln];
            cst = fv * cst + iv * gv;
            shc[ln] = ov * tanh_f(cst);
        }
        __syncthreads();                               // b2

        // ---- layer 1, half-dot: pb1 + [h0|h1][64h:64h+64] . rc1
        const float4* hc4 = (const float4*)(shc + 64 * h);
        float d0 = pb1, d1 = 0.0f, d2 = 0.0f, d3 = 0.0f;
        #pragma unroll
        for (int k = 0; k < 16; ++k) {
            float4 v = hc4[k];
            d0 += v.x * rc1[4 * k + 0];
            d1 += v.y * rc1[4 * k + 1];
            d2 += v.z * rc1[4 * k + 2];
            d3 += v.w * rc1[4 * k + 3];
        }
        float zq = (d0 + d1) + (d2 + d3);
        float z1 = zq + __shfl_xor(zq, 1);
        float av1 = ((g >> 6) == 2) ? tanh_f(z1) : sigm_f(z1);
        if (h == 0) sg1[g] = av1;
        __syncthreads();                               // b3

        if (wv == 1) {  // wave 1: update c1, h1. Next readers of shc[64:128]
            // are behind b2 of step t+1, which wave 1 reaches only after this.
            float iv = sg1[ln], fv = sg1[64 + ln], gv = sg1[128 + ln], ov = sg1[192 + ln];
            cst = fv * cst + iv * gv;
            shc[HID + ln] = ov * tanh_f(cst);
        }
    }
    __syncthreads();

    // ---- FC + softmax on final h1 (= shc[64:128]) --------------------------
    if (t0 < NCLS) {
        float acc = fcb[t0];
        const float* w = fcw + t0 * HID;
        #pragma unroll
        for (int k = 0; k < HID; ++k) acc += shc[HID + k] * w[k];
        sg0[t0] = acc;
    }
    __syncthreads();
    if (t0 == 0) {
        float l0 = sg0[0], l1 = sg0[1], l2 = sg0[2], l3 = sg0[3];
        float m = fmaxf(fmaxf(l0, l1), fmaxf(l2, l3));
        float e0 = __expf(l0 - m), e1 = __expf(l1 - m);
        float e2 = __expf(l2 - m), e3 = __expf(l3 - m);
        float inv = rcp_f(e0 + e1 + e2 + e3);
        out[b * NCLS + 0] = e0 * inv;
        out[b * NCLS + 1] = e1 * inv;
        out[b * NCLS + 2] = e2 * inv;
        out[b * NCLS + 3] = e3 * inv;
    }
}

extern "C" void kernel_launch(void* const* d_in, const int* in_sizes, int n_in,
                              void* d_out, int out_size, void* d_ws, size_t ws_size,
                              hipStream_t stream) {
    const float* x    = (const float*)d_in[0];
    const float* wih0 = (const float*)d_in[1];
    const float* whh0 = (const float*)d_in[2];
    const float* bih0 = (const float*)d_in[3];
    const float* bhh0 = (const float*)d_in[4];
    const float* wih1 = (const float*)d_in[5];
    const float* whh1 = (const float*)d_in[6];
    const float* bih1 = (const float*)d_in[7];
    const float* bhh1 = (const float*)d_in[8];
    const float* fcw  = (const float*)d_in[9];
    const float* fcb  = (const float*)d_in[10];
    float* out = (float*)d_out;

    lstm2_fused<<<BATCH, NT, 0, stream>>>(x, wih0, whh0, bih0, bhh0,
                                          wih1, whh1, bih1, bhh1,
                                          fcw, fcb, out);
}

// Round 3
// 2133.390 us; speedup vs baseline: 4.3235x; 4.3235x over previous
//
#include <hip/hip_runtime.h>

typedef _Float16 f16;
typedef _Float16 f16x4 __attribute__((ext_vector_type(4)));
typedef _Float16 f16x8 __attribute__((ext_vector_type(8)));
typedef float    f32x4 __attribute__((ext_vector_type(4)));

#define BATCH 1024
#define TSEQ  2048
#define DIN   15
#define HID   64
#define BT    2              // batch rows per block
#define NBLK  (BATCH / BT)   // 512 blocks -> 2 per CU
#define NT    256            // 4 waves
#define CHUNK 32             // timesteps of x staged per load
#define NCLS  4

__device__ __forceinline__ float rcp_f(float x)  { return __builtin_amdgcn_rcpf(x); }
__device__ __forceinline__ float sig_f(float z)  { return rcp_f(1.0f + __expf(-z)); }
__device__ __forceinline__ float tanh_f(float z) { return 1.0f - 2.0f * rcp_f(1.0f + __expf(2.0f * z)); }

__device__ __forceinline__ f16x8 cvt8(const float* p) {
    float4 lo = ((const float4*)p)[0];
    float4 hi = ((const float4*)p)[1];
    f16x8 r;
    r[0] = (f16)lo.x; r[1] = (f16)lo.y; r[2] = (f16)lo.z; r[3] = (f16)lo.w;
    r[4] = (f16)hi.x; r[5] = (f16)hi.y; r[6] = (f16)hi.z; r[7] = (f16)hi.w;
    return r;
}

// MFMA fragment conventions (v_mfma_f32_16x16x32_f16):
//   A (16Mx32K): lane l holds A[l&15][8*(l>>4)+i], i=0..7
//   B (32Kx16N): lane l holds B[8*(l>>4)+i][l&15]
//   C (16Mx16N): lane l holds C[(l>>4)*4+r][l&15], r=0..3   (m89-verified)
// gates[b][n] = sum_k in[b][k] * W[n][k]:  A = in (M=batch), B[k][n] = W[n][k].
// Wave w owns N-tiles {w, w+4, w+8, w+12} = gates i/f/g/o of j in [16w,16w+16):
// all four gate values for (b,j) land in the SAME lane -> per-lane c/h update.
__global__ __launch_bounds__(NT, 2)
void lstm2_mfma(const float* __restrict__ x,
                const float* __restrict__ wih0, const float* __restrict__ whh0,
                const float* __restrict__ bih0, const float* __restrict__ bhh0,
                const float* __restrict__ wih1, const float* __restrict__ whh1,
                const float* __restrict__ bih1, const float* __restrict__ bhh1,
                const float* __restrict__ fcw,  const float* __restrict__ fcb,
                float* __restrict__ out)
{
    const int tid = threadIdx.x;
    const int w   = tid >> 6;       // wave 0..3
    const int l   = tid & 63;
    const int m16 = l & 15;         // A-row / B-col / C-col index
    const int lg  = l >> 4;         // k-group
    const int bbase = blockIdx.x * BT;

    // LDS: x chunk (zero-padded to 16 rows x 16 k), double-buffered h0/h1 (f16)
    __shared__ __align__(16) f16 sx [CHUNK][16][16];   // 16 KB
    __shared__ __align__(16) f16 sh0[2][16][HID];      //  4 KB
    __shared__ __align__(16) f16 sh1[2][16][HID];      //  4 KB

    {   // zero-init: ghost rows stay 0 forever; h(t=-1) = 0
        int* z = (int*)&sx[0][0][0];
        #pragma unroll 4
        for (int i = tid; i < (int)(sizeof(sx) / 4); i += NT) z[i] = 0;
        int* z0 = (int*)&sh0[0][0][0];
        for (int i = tid; i < (int)(sizeof(sh0) / 4); i += NT) z0[i] = 0;
        int* z1 = (int*)&sh1[0][0][0];
        for (int i = tid; i < (int)(sizeof(sh1) / 4); i += NT) z1[i] = 0;
    }

    // ---- step-invariant weight B-fragments (the only big register state) ----
    f16x4 bx[4];        // wih0, K=16 (padded from 15)
    f16x8 bh0[4][2];    // whh0, K=64
    f16x8 bh1[4][4];    // [wih1|whh1], K=128
    float pb0[4], pb1[4];
    #pragma unroll
    for (int i = 0; i < 4; ++i) {
        const int n = 16 * (w + 4 * i) + m16;   // gate row 0..255
        #pragma unroll
        for (int j = 0; j < 4; ++j) {
            int k = 4 * lg + j;
            bx[i][j] = (f16)((k < DIN) ? wih0[n * DIN + k] : 0.0f);
        }
        #pragma unroll
        for (int f = 0; f < 2; ++f)
            bh0[i][f] = cvt8(whh0 + n * HID + 32 * f + 8 * lg);
        #pragma unroll
        for (int f = 0; f < 4; ++f) {
            int k0 = 32 * f + 8 * lg;   // K index in [h0|h1] concat
            const float* src = (k0 < HID) ? (wih1 + n * HID + k0)
                                          : (whh1 + n * HID + (k0 - HID));
            bh1[i][f] = cvt8(src);
        }
        pb0[i] = bih0[n] + bhh0[n];
        pb1[i] = bih1[n] + bhh1[n];
    }

    float c0r[2] = {0.0f, 0.0f};   // c-state, batch rows (4*lg+0, 4*lg+1)
    float c1r[2] = {0.0f, 0.0f};

    const float* xb = x + (size_t)bbase * TSEQ * DIN;

    const uint rb = (uint)(m16 * 128);            // h row byte offset for A-frag
    const uint sz = ((uint)(m16 & 7)) << 4;       // XOR swizzle for that row
    __syncthreads();   // zero-init visible

    for (int t = 0; t < TSEQ; ++t) {
        const int tc = t & (CHUNK - 1);
        if (tc == 0) {   // stage 32 steps of x (valid rows 0..1, k<15 only)
            for (int idx = tid; idx < CHUNK * BT * DIN; idx += NT) {
                int s = idx / (BT * DIN);
                int r = idx - s * (BT * DIN);
                int b = r / DIN;
                int k = r - b * DIN;
                sx[s][b][k] = (f16)xb[(size_t)b * TSEQ * DIN + (size_t)(t + s) * DIN + k];
            }
            __syncthreads();
        }
        const int pw = t & 1, pr = pw ^ 1;

        // ================= layer 0:  [x_t | h0(t-1)]  K=16+64 =================
        f16x4 ax = *(const f16x4*)&sx[tc][m16][4 * lg];
        const char* h0r = (const char*)&sh0[pr][0][0];
        f16x8 a0 = *(const f16x8*)(h0r + ((rb +      16 * lg) ^ sz));
        f16x8 a1 = *(const f16x8*)(h0r + ((rb + 64 + 16 * lg) ^ sz));

        f32x4 acc[4];
        #pragma unroll
        for (int i = 0; i < 4; ++i) {
            acc[i] = (f32x4){pb0[i], pb0[i], pb0[i], pb0[i]};
            acc[i] = __builtin_amdgcn_mfma_f32_16x16x16f16(ax, bx[i], acc[i], 0, 0, 0);
            acc[i] = __builtin_amdgcn_mfma_f32_16x16x32_f16(a0, bh0[i][0], acc[i], 0, 0, 0);
            acc[i] = __builtin_amdgcn_mfma_f32_16x16x32_f16(a1, bh0[i][1], acc[i], 0, 0, 0);
        }
        // activation on C-regs 0,1 only (batch rows 4*lg+{0,1}; valid for lg==0)
        char* h0w = (char*)&sh0[pw][0][0];
        #pragma unroll
        for (int r = 0; r < 2; ++r) {
            float iv = sig_f (acc[0][r]);
            float fv = sig_f (acc[1][r]);
            float gv = tanh_f(acc[2][r]);
            float ov = sig_f (acc[3][r]);
            c0r[r] = fv * c0r[r] + iv * gv;
            float hv = ov * tanh_f(c0r[r]);
            int b = 4 * lg + r;
            uint off = ((uint)(b * 128 + (16 * w + m16) * 2)) ^ (((uint)(b & 7)) << 4);
            *(f16*)(h0w + off) = (f16)hv;
        }
        __syncthreads();                                    // h0(t) ready

        // ================= layer 1:  [h0(t) | h1(t-1)]  K=128 =================
        const char* hc0 = (const char*)&sh0[pw][0][0];
        const char* hc1 = (const char*)&sh1[pr][0][0];
        f16x8 e0 = *(const f16x8*)(hc0 + ((rb +      16 * lg) ^ sz));
        f16x8 e1 = *(const f16x8*)(hc0 + ((rb + 64 + 16 * lg) ^ sz));
        f16x8 e2 = *(const f16x8*)(hc1 + ((rb +      16 * lg) ^ sz));
        f16x8 e3 = *(const f16x8*)(hc1 + ((rb + 64 + 16 * lg) ^ sz));

        f32x4 bcc[4];
        #pragma unroll
        for (int i = 0; i < 4; ++i) {
            bcc[i] = (f32x4){pb1[i], pb1[i], pb1[i], pb1[i]};
            bcc[i] = __builtin_amdgcn_mfma_f32_16x16x32_f16(e0, bh1[i][0], bcc[i], 0, 0, 0);
            bcc[i] = __builtin_amdgcn_mfma_f32_16x16x32_f16(e1, bh1[i][1], bcc[i], 0, 0, 0);
            bcc[i] = __builtin_amdgcn_mfma_f32_16x16x32_f16(e2, bh1[i][2], bcc[i], 0, 0, 0);
            bcc[i] = __builtin_amdgcn_mfma_f32_16x16x32_f16(e3, bh1[i][3], bcc[i], 0, 0, 0);
        }
        char* h1w = (char*)&sh1[pw][0][0];
        #pragma unroll
        for (int r = 0; r < 2; ++r) {
            float iv = sig_f (bcc[0][r]);
            float fv = sig_f (bcc[1][r]);
            float gv = tanh_f(bcc[2][r]);
            float ov = sig_f (bcc[3][r]);
            c1r[r] = fv * c1r[r] + iv * gv;
            float hv = ov * tanh_f(c1r[r]);
            int b = 4 * lg + r;
            uint off = ((uint)(b * 128 + (16 * w + m16) * 2)) ^ (((uint)(b & 7)) << 4);
            *(f16*)(h1w + off) = (f16)hv;
        }
        __syncthreads();                                    // h1(t) ready
    }

    // ---- FC + softmax on final h1 (in sh1[(TSEQ-1)&1] = sh1[1]) ------------
    float* sl = (float*)&sx[0][0][0];   // reuse as logit buffer
    if (tid < BT * NCLS) {
        int b = tid >> 2, c = tid & 3;
        const char* h1b = (const char*)&sh1[1][0][0];
        float acc = fcb[c];
        for (int j = 0; j < HID; ++j) {
            uint off = ((uint)(b * 128 + j * 2)) ^ (((uint)(b & 7)) << 4);
            acc += (float)(*(const f16*)(h1b + off)) * fcw[c * HID + j];
        }
        sl[tid] = acc;
    }
    __syncthreads();
    if (tid < BT) {
        float l0 = sl[tid * 4 + 0], l1 = sl[tid * 4 + 1];
        float l2 = sl[tid * 4 + 2], l3 = sl[tid * 4 + 3];
        float m = fmaxf(fmaxf(l0, l1), fmaxf(l2, l3));
        float e0 = __expf(l0 - m), e1 = __expf(l1 - m);
        float e2 = __expf(l2 - m), e3 = __expf(l3 - m);
        float inv = rcp_f(e0 + e1 + e2 + e3);
        out[(bbase + tid) * NCLS + 0] = e0 * inv;
        out[(bbase + tid) * NCLS + 1] = e1 * inv;
        out[(bbase + tid) * NCLS + 2] = e2 * inv;
        out[(bbase + tid) * NCLS + 3] = e3 * inv;
    }
}

extern "C" void kernel_launch(void* const* d_in, const int* in_sizes, int n_in,
                              void* d_out, int out_size, void* d_ws, size_t ws_size,
                              hipStream_t stream) {
    (void)in_sizes; (void)n_in; (void)out_size; (void)d_ws; (void)ws_size;
    const float* x    = (const float*)d_in[0];
    const float* wih0 = (const float*)d_in[1];
    const float* whh0 = (const float*)d_in[2];
    const float* bih0 = (const float*)d_in[3];
    const float* bhh0 = (const float*)d_in[4];
    const float* wih1 = (const float*)d_in[5];
    const float* whh1 = (const float*)d_in[6];
    const float* bih1 = (const float*)d_in[7];
    const float* bhh1 = (const float*)d_in[8];
    const float* fcw  = (const float*)d_in[9];
    const float* fcb  = (const float*)d_in[10];
    float* out = (float*)d_out;

    lstm2_mfma<<<NBLK, NT, 0, stream>>>(x, wih0, whh0, bih0, bhh0,
                                        wih1, whh1, bih1, bhh1,
                                        fcw, fcb, out);
}

// Round 4
// 2048.403 us; speedup vs baseline: 4.5029x; 1.0415x over previous
//
#include <hip/hip_runtime.h>

typedef _Float16 f16;
typedef _Float16 f16x4 __attribute__((ext_vector_type(4)));
typedef _Float16 f16x8 __attribute__((ext_vector_type(8)));
typedef float    f32x4 __attribute__((ext_vector_type(4)));

#define BATCH 1024
#define TSEQ  2048
#define DIN   15
#define HID   64
#define BT    2              // real batch rows per block (M=16 MFMA, rest ghost)
#define NBLK  (BATCH / BT)   // 512 blocks -> 2 per CU
#define NT    256            // 4 waves
#define CHUNK 16             // timesteps of x per staging chunk
#define NCLS  4

__device__ __forceinline__ float rcp_f(float x)  { return __builtin_amdgcn_rcpf(x); }
__device__ __forceinline__ float sig_f(float z)  { return rcp_f(1.0f + __expf(-z)); }
__device__ __forceinline__ float tanh_f(float z) { return 1.0f - 2.0f * rcp_f(1.0f + __expf(2.0f * z)); }

__device__ __forceinline__ f16x8 cvt8(const float* p) {
    float4 lo = ((const float4*)p)[0];
    float4 hi = ((const float4*)p)[1];
    f16x8 r;
    r[0] = (f16)lo.x; r[1] = (f16)lo.y; r[2] = (f16)lo.z; r[3] = (f16)lo.w;
    r[4] = (f16)hi.x; r[5] = (f16)hi.y; r[6] = (f16)hi.z; r[7] = (f16)hi.w;
    return r;
}

// Pipelined 2-layer LSTM, ONE barrier per timestep.
// Iteration k computes gates0(t=k+1) from {x(k+1), h0(k)} AND gates1(t=k)
// from {h0(k), h1(k-1)} -- both independent given h0(k). h0(k), h1(k-1) were
// both written in iteration k-1 into the SAME double-buffered LDS tile
// sh[(k+1)&1][16 rows][128 cols] ([h0 | h1] concat), so one barrier covers all.
// MFMA conventions (validated in round 3):
//   16x16x32 A: lane l holds A[l&15][8*(l>>4)+i];  16x16x16 A: A[l&15][4*(l>>4)+i]
//   C: lane l holds C[(l>>4)*4+r][l&15]
// Wave w owns N-tiles {w,w+4,w+8,w+12}: gates i/f/g/o of hidden j=16w+(l&15)
// land in the same lane -> per-lane c/h update. Ghost batch rows (>=BT) stay 0
// in LDS (never written), polluting only ghost C rows.
__global__ __launch_bounds__(NT, 2)
void lstm2_pipe(const float* __restrict__ x,
                const float* __restrict__ wih0, const float* __restrict__ whh0,
                const float* __restrict__ bih0, const float* __restrict__ bhh0,
                const float* __restrict__ wih1, const float* __restrict__ whh1,
                const float* __restrict__ bih1, const float* __restrict__ bhh1,
                const float* __restrict__ fcw,  const float* __restrict__ fcb,
                float* __restrict__ out)
{
    const int tid = threadIdx.x;
    const int w   = tid >> 6;
    const int l   = tid & 63;
    const int m16 = l & 15;
    const int lg  = l >> 4;
    const int bbase = blockIdx.x * BT;

    __shared__ __align__(16) f16 sx[2][CHUNK][16][16];  // 16 KB, dbuf x chunks
    __shared__ __align__(16) f16 sh[2][16][128];        //  8 KB, dbuf [h0|h1]

    {   // zero LDS once: ghost rows stay 0 forever; h(-1) = 0
        int4 zero = {0, 0, 0, 0};
        int4* z = (int4*)sx;
        #pragma unroll
        for (int i = 0; i < 4; ++i) z[tid + NT * i] = zero;   // 1024 int4
        int4* zh = (int4*)sh;
        #pragma unroll
        for (int i = 0; i < 2; ++i) zh[tid + NT * i] = zero;  // 512 int4
    }

    // ---- step-invariant weight B-fragments ---------------------------------
    f16x4 bx[4];        // wih0, K=16 (padded from 15 with 0)
    f16x8 bh0[4][2];    // whh0, K=64
    f16x8 bh1[4][4];    // [wih1|whh1] concat, K=128
    float pb0[4], pb1[4];
    #pragma unroll
    for (int i = 0; i < 4; ++i) {
        const int n = 16 * (w + 4 * i) + m16;   // gate row 0..255
        #pragma unroll
        for (int j = 0; j < 4; ++j) {
            int k = 4 * lg + j;
            bx[i][j] = (f16)((k < DIN) ? wih0[n * DIN + k] : 0.0f);
        }
        #pragma unroll
        for (int f = 0; f < 2; ++f)
            bh0[i][f] = cvt8(whh0 + n * HID + 32 * f + 8 * lg);
        #pragma unroll
        for (int f = 0; f < 4; ++f) {
            int k0 = 32 * f + 8 * lg;
            const float* src = (k0 < HID) ? (wih1 + n * HID + k0)
                                          : (whh1 + n * HID + (k0 - HID));
            bh1[i][f] = cvt8(src);
        }
        pb0[i] = bih0[n] + bhh0[n];
        pb1[i] = bih1[n] + bhh1[n];
    }

    const float* xb = x + (size_t)bbase * TSEQ * DIN;

    // ---- prologue staging: chunks 0 and 1 ----------------------------------
    #pragma unroll
    for (int j = 0; j < 4; ++j) {
        int idx = tid + NT * j;
        if (idx < 2 * CHUNK * BT * DIN) {           // 960
            int cn = idx / (CHUNK * BT * DIN);
            int r  = idx % (CHUNK * BT * DIN);
            int s  = r / (BT * DIN);
            int r2 = r % (BT * DIN);
            int b  = r2 / DIN;
            int kk = r2 % DIN;
            sx[cn][s][b][kk] =
                (f16)xb[(size_t)b * TSEQ * DIN + (size_t)(cn * CHUNK + s) * DIN + kk];
        }
    }

    float c0r[2] = {0.0f, 0.0f};
    float c1r[2] = {0.0f, 0.0f};
    float stg0 = 0.0f, stg1 = 0.0f;   // T14-style staging registers

    const uint rb  = (uint)(m16 * 256);          // A-frag row base (bytes)
    const uint szw = ((uint)(m16 & 7)) << 4;     // XOR bank swizzle

    __syncthreads();   // zero-init + prologue x staging visible

    // ---- prologue compute: h0(0) = act(bias + x(0).W), h0(-1)=0 ------------
    {
        f16x4 ax = *(const f16x4*)&sx[0][0][m16][4 * lg];
        f32x4 acc[4];
        #pragma unroll
        for (int i = 0; i < 4; ++i) {
            acc[i] = (f32x4){pb0[i], pb0[i], pb0[i], pb0[i]};
            acc[i] = __builtin_amdgcn_mfma_f32_16x16x16f16(ax, bx[i], acc[i], 0, 0, 0);
        }
        char* hw = (char*)&sh[1][0][0];   // iter 0 reads buf 1
        #pragma unroll
        for (int r = 0; r < 2; ++r) {
            float i0 = sig_f(acc[0][r]);
            float g0 = tanh_f(acc[2][r]);
            float o0 = sig_f(acc[3][r]);
            c0r[r] = i0 * g0;             // c0(-1) = 0
            float h0v = o0 * tanh_f(c0r[r]);
            if (lg == 0) {
                uint jb = (uint)(2 * (16 * w + m16));
                *(f16*)(hw + r * 256 + (jb ^ (((uint)r) << 4))) = (f16)h0v;
            }
        }
    }

    // ---- main loop: iter k -> gates0(k+1) + gates1(k), ONE barrier ---------
    for (int k = 0; k < TSEQ; ++k) {
        __syncthreads();   // sh[pr] (h0(k), h1(k-1)) and staged x visible
        const int t  = k + 1;
        const int pr = t & 1;
        const int pw = k & 1;

        // stage trigger: issue global loads for chunk (t>>4)+1
        if ((t & (CHUNK - 1)) == 0 && t + CHUNK < TSEQ) {
            const int tb = t + CHUNK;
            {
                int s = tid / 30, r2 = tid % 30, b = r2 / 15, kk = r2 % 15;
                stg0 = xb[(size_t)b * TSEQ * DIN + (size_t)(tb + s) * DIN + kk];
            }
            if (tid + NT < CHUNK * BT * DIN) {
                int i2 = tid + NT;
                int s = i2 / 30, r2 = i2 % 30, b = r2 / 15, kk = r2 % 15;
                stg1 = xb[(size_t)b * TSEQ * DIN + (size_t)(tb + s) * DIN + kk];
            }
        }
        // stage write: 8 iterations later, vmcnt long drained
        if ((t & (CHUNK - 1)) == 8 && t + 8 < TSEQ) {
            const int cb = ((t >> 4) + 1) & 1;
            {
                int s = tid / 30, r2 = tid % 30, b = r2 / 15, kk = r2 % 15;
                sx[cb][s][b][kk] = (f16)stg0;
            }
            if (tid + NT < CHUNK * BT * DIN) {
                int i2 = tid + NT;
                int s = i2 / 30, r2 = i2 % 30, b = r2 / 15, kk = r2 % 15;
                sx[cb][s][b][kk] = (f16)stg1;
            }
        }

        // ---- A-fragments (h0 half shared between both layers) ----
        const int bxf = (t >> 4) & 1;
        const int ts  = t & (CHUNK - 1);
        f16x4 ax = *(const f16x4*)&sx[bxf][ts][m16][4 * lg];
        const char* hb = (const char*)&sh[pr][0][0];
        f16x8 a0 = *(const f16x8*)(hb + ((rb +       16 * lg) ^ szw));  // h0 k 0..31
        f16x8 a1 = *(const f16x8*)(hb + ((rb +  64 + 16 * lg) ^ szw));  // h0 k 32..63
        f16x8 e2 = *(const f16x8*)(hb + ((rb + 128 + 16 * lg) ^ szw));  // h1 k 0..31
        f16x8 e3 = *(const f16x8*)(hb + ((rb + 192 + 16 * lg) ^ szw));  // h1 k 32..63

        // ---- both layers' MFMAs (8 independent chains, interleaved) ----
        f32x4 acc[4], bcc[4];
        #pragma unroll
        for (int i = 0; i < 4; ++i) {
            acc[i] = (f32x4){pb0[i], pb0[i], pb0[i], pb0[i]};
            acc[i] = __builtin_amdgcn_mfma_f32_16x16x16f16(ax, bx[i], acc[i], 0, 0, 0);
            acc[i] = __builtin_amdgcn_mfma_f32_16x16x32_f16(a0, bh0[i][0], acc[i], 0, 0, 0);
            acc[i] = __builtin_amdgcn_mfma_f32_16x16x32_f16(a1, bh0[i][1], acc[i], 0, 0, 0);
            bcc[i] = (f32x4){pb1[i], pb1[i], pb1[i], pb1[i]};
            bcc[i] = __builtin_amdgcn_mfma_f32_16x16x32_f16(a0, bh1[i][0], bcc[i], 0, 0, 0);
            bcc[i] = __builtin_amdgcn_mfma_f32_16x16x32_f16(a1, bh1[i][1], bcc[i], 0, 0, 0);
            bcc[i] = __builtin_amdgcn_mfma_f32_16x16x32_f16(e2, bh1[i][2], bcc[i], 0, 0, 0);
            bcc[i] = __builtin_amdgcn_mfma_f32_16x16x32_f16(e3, bh1[i][3], bcc[i], 0, 0, 0);
        }

        // ---- activations: c0/h0 for t=k+1, c1/h1 for t=k ----
        // (k = TSEQ-1 computes a dummy layer0 from stale-but-finite x; its h0
        //  write and c0 update are never consumed.)
        char* hw = (char*)&sh[pw][0][0];
        #pragma unroll
        for (int r = 0; r < 2; ++r) {
            float i0 = sig_f (acc[0][r]);
            float f0 = sig_f (acc[1][r]);
            float g0 = tanh_f(acc[2][r]);
            float o0 = sig_f (acc[3][r]);
            c0r[r] = f0 * c0r[r] + i0 * g0;
            float h0v = o0 * tanh_f(c0r[r]);

            float i1 = sig_f (bcc[0][r]);
            float f1 = sig_f (bcc[1][r]);
            float g1 = tanh_f(bcc[2][r]);
            float o1 = sig_f (bcc[3][r]);
            c1r[r] = f1 * c1r[r] + i1 * g1;
            float h1v = o1 * tanh_f(c1r[r]);

            if (lg == 0) {   // only real batch rows written; ghosts stay 0
                uint cswz = ((uint)r) << 4;
                uint jb   = (uint)(2 * (16 * w + m16));
                *(f16*)(hw + r * 256 + ((jb      ) ^ cswz)) = (f16)h0v;
                *(f16*)(hw + r * 256 + ((jb + 128) ^ cswz)) = (f16)h1v;
            }
        }
    }
    __syncthreads();

    // ---- FC + softmax on final h1 = sh[1] cols 64..127 ---------------------
    float* sl = (float*)&sx[0][0][0][0];
    if (tid < BT * NCLS) {
        int b = tid >> 2, c = tid & 3;
        const char* h1b = (const char*)&sh[1][0][0];
        float acc = fcb[c];
        for (int j = 0; j < HID; ++j) {
            uint off = (uint)(b * 256) + (((uint)(128 + 2 * j)) ^ (((uint)(b & 7)) << 4));
            acc += (float)(*(const f16*)(h1b + off)) * fcw[c * HID + j];
        }
        sl[tid] = acc;
    }
    __syncthreads();
    if (tid < BT) {
        float l0 = sl[tid * 4 + 0], l1 = sl[tid * 4 + 1];
        float l2 = sl[tid * 4 + 2], l3 = sl[tid * 4 + 3];
        float m = fmaxf(fmaxf(l0, l1), fmaxf(l2, l3));
        float e0 = __expf(l0 - m), e1 = __expf(l1 - m);
        float e2 = __expf(l2 - m), e3 = __expf(l3 - m);
        float inv = rcp_f(e0 + e1 + e2 + e3);
        out[(bbase + tid) * NCLS + 0] = e0 * inv;
        out[(bbase + tid) * NCLS + 1] = e1 * inv;
        out[(bbase + tid) * NCLS + 2] = e2 * inv;
        out[(bbase + tid) * NCLS + 3] = e3 * inv;
    }
}

extern "C" void kernel_launch(void* const* d_in, const int* in_sizes, int n_in,
                              void* d_out, int out_size, void* d_ws, size_t ws_size,
                              hipStream_t stream) {
    (void)in_sizes; (void)n_in; (void)out_size; (void)d_ws; (void)ws_size;
    const float* x    = (const float*)d_in[0];
    const float* wih0 = (const float*)d_in[1];
    const float* whh0 = (const float*)d_in[2];
    const float* bih0 = (const float*)d_in[3];
    const float* bhh0 = (const float*)d_in[4];
    const float* wih1 = (const float*)d_in[5];
    const float* whh1 = (const float*)d_in[6];
    const float* bih1 = (const float*)d_in[7];
    const float* bhh1 = (const float*)d_in[8];
    const float* fcw  = (const float*)d_in[9];
    const float* fcb  = (const float*)d_in[10];
    float* out = (float*)d_out;

    lstm2_pipe<<<NBLK, NT, 0, stream>>>(x, wih0, whh0, bih0, bhh0,
                                        wih1, whh1, bih1, bhh1,
                                        fcw, fcb, out);
}

// Round 5
// 2045.445 us; speedup vs baseline: 4.5094x; 1.0014x over previous
//
#include <hip/hip_runtime.h>

typedef _Float16 f16;
typedef _Float16 f16x4 __attribute__((ext_vector_type(4)));
typedef _Float16 f16x8 __attribute__((ext_vector_type(8)));
typedef float    f32x4 __attribute__((ext_vector_type(4)));

#define BATCH 1024
#define TSEQ  2048
#define DIN   15
#define HID   64
#define BT    2              // real batch rows per block (M=16 MFMA, rest ghost)
#define NBLK  (BATCH / BT)   // 512 blocks -> 2 per CU
#define NT    256            // 4 waves
#define CHUNK 16             // timesteps of x per staging chunk
#define NCLS  4

__device__ __forceinline__ float rcp_f(float x)  { return __builtin_amdgcn_rcpf(x); }
__device__ __forceinline__ float sig_f(float z)  { return rcp_f(1.0f + __expf(-z)); }
__device__ __forceinline__ float tanh_f(float z) { return 1.0f - 2.0f * rcp_f(1.0f + __expf(2.0f * z)); }

__device__ __forceinline__ f16x8 cvt8(const float* p) {
    float4 lo = ((const float4*)p)[0];
    float4 hi = ((const float4*)p)[1];
    f16x8 r;
    r[0] = (f16)lo.x; r[1] = (f16)lo.y; r[2] = (f16)lo.z; r[3] = (f16)lo.w;
    r[4] = (f16)hi.x; r[5] = (f16)hi.y; r[6] = (f16)hi.z; r[7] = (f16)hi.w;
    return r;
}

// Pipelined 2-layer LSTM, ONE barrier per timestep.
// Iteration k computes gates0(t=k+1) from {x(k+1), h0(k)} AND gates1(t=k)
// from {h0(k), h1(k-1)} -- both independent given h0(k). h0(k), h1(k-1) were
// both written in iteration k-1 into the SAME double-buffered LDS tile
// sh[(k+1)&1][16 rows][128 cols] ([h0 | h1] concat), so one barrier covers all.
// MFMA conventions (validated in round 3):
//   16x16x32 A: lane l holds A[l&15][8*(l>>4)+i];  16x16x16 A: A[l&15][4*(l>>4)+i]
//   C: lane l holds C[(l>>4)*4+r][l&15]
// Wave w owns N-tiles {w,w+4,w+8,w+12}: gates i/f/g/o of hidden j=16w+(l&15)
// land in the same lane -> per-lane c/h update. Ghost batch rows (>=BT) stay 0
// in LDS (never written), polluting only ghost C rows.
__global__ __launch_bounds__(NT, 2)
void lstm2_pipe(const float* __restrict__ x,
                const float* __restrict__ wih0, const float* __restrict__ whh0,
                const float* __restrict__ bih0, const float* __restrict__ bhh0,
                const float* __restrict__ wih1, const float* __restrict__ whh1,
                const float* __restrict__ bih1, const float* __restrict__ bhh1,
                const float* __restrict__ fcw,  const float* __restrict__ fcb,
                float* __restrict__ out)
{
    const int tid = threadIdx.x;
    const int w   = tid >> 6;
    const int l   = tid & 63;
    const int m16 = l & 15;
    const int lg  = l >> 4;
    const int bbase = blockIdx.x * BT;

    __shared__ __align__(16) f16 sx[2][CHUNK][16][16];  // 16 KB, dbuf x chunks
    __shared__ __align__(16) f16 sh[2][16][128];        //  8 KB, dbuf [h0|h1]

    {   // zero LDS once: ghost rows stay 0 forever; h(-1) = 0
        int4 zero = {0, 0, 0, 0};
        int4* z = (int4*)sx;
        #pragma unroll
        for (int i = 0; i < 4; ++i) z[tid + NT * i] = zero;   // 1024 int4
        int4* zh = (int4*)sh;
        #pragma unroll
        for (int i = 0; i < 2; ++i) zh[tid + NT * i] = zero;  // 512 int4
    }

    // ---- step-invariant weight B-fragments ---------------------------------
    f16x4 bx[4];        // wih0, K=16 (padded from 15 with 0)
    f16x8 bh0[4][2];    // whh0, K=64
    f16x8 bh1[4][4];    // [wih1|whh1] concat, K=128
    float pb0[4], pb1[4];
    #pragma unroll
    for (int i = 0; i < 4; ++i) {
        const int n = 16 * (w + 4 * i) + m16;   // gate row 0..255
        #pragma unroll
        for (int j = 0; j < 4; ++j) {
            int k = 4 * lg + j;
            bx[i][j] = (f16)((k < DIN) ? wih0[n * DIN + k] : 0.0f);
        }
        #pragma unroll
        for (int f = 0; f < 2; ++f)
            bh0[i][f] = cvt8(whh0 + n * HID + 32 * f + 8 * lg);
        #pragma unroll
        for (int f = 0; f < 4; ++f) {
            int k0 = 32 * f + 8 * lg;
            const float* src = (k0 < HID) ? (wih1 + n * HID + k0)
                                          : (whh1 + n * HID + (k0 - HID));
            bh1[i][f] = cvt8(src);
        }
        pb0[i] = bih0[n] + bhh0[n];
        pb1[i] = bih1[n] + bhh1[n];
    }

    const float* xb = x + (size_t)bbase * TSEQ * DIN;

    // ---- prologue staging: chunks 0 and 1 ----------------------------------
    #pragma unroll
    for (int j = 0; j < 4; ++j) {
        int idx = tid + NT * j;
        if (idx < 2 * CHUNK * BT * DIN) {           // 960
            int cn = idx / (CHUNK * BT * DIN);
            int r  = idx % (CHUNK * BT * DIN);
            int s  = r / (BT * DIN);
            int r2 = r % (BT * DIN);
            int b  = r2 / DIN;
            int kk = r2 % DIN;
            sx[cn][s][b][kk] =
                (f16)xb[(size_t)b * TSEQ * DIN + (size_t)(cn * CHUNK + s) * DIN + kk];
        }
    }

    float c0r[2] = {0.0f, 0.0f};
    float c1r[2] = {0.0f, 0.0f};
    float stg0 = 0.0f, stg1 = 0.0f;   // T14-style staging registers

    const uint rb  = (uint)(m16 * 256);          // A-frag row base (bytes)
    const uint szw = ((uint)(m16 & 7)) << 4;     // XOR bank swizzle

    __syncthreads();   // zero-init + prologue x staging visible

    // ---- prologue compute: h0(0) = act(bias + x(0).W), h0(-1)=0 ------------
    {
        f16x4 ax = *(const f16x4*)&sx[0][0][m16][4 * lg];
        f32x4 acc[4];
        #pragma unroll
        for (int i = 0; i < 4; ++i) {
            acc[i] = (f32x4){pb0[i], pb0[i], pb0[i], pb0[i]};
            acc[i] = __builtin_amdgcn_mfma_f32_16x16x16f16(ax, bx[i], acc[i], 0, 0, 0);
        }
        char* hw = (char*)&sh[1][0][0];   // iter 0 reads buf 1
        #pragma unroll
        for (int r = 0; r < 2; ++r) {
            float i0 = sig_f(acc[0][r]);
            float g0 = tanh_f(acc[2][r]);
            float o0 = sig_f(acc[3][r]);
            c0r[r] = i0 * g0;             // c0(-1) = 0
            float h0v = o0 * tanh_f(c0r[r]);
            if (lg == 0) {
                uint jb = (uint)(2 * (16 * w + m16));
                *(f16*)(hw + r * 256 + (jb ^ (((uint)r) << 4))) = (f16)h0v;
            }
        }
    }

    // ---- main loop: iter k -> gates0(k+1) + gates1(k), ONE barrier ---------
    for (int k = 0; k < TSEQ; ++k) {
        __syncthreads();   // sh[pr] (h0(k), h1(k-1)) and staged x visible
        const int t  = k + 1;
        const int pr = t & 1;
        const int pw = k & 1;

        // stage trigger: issue global loads for chunk (t>>4)+1
        if ((t & (CHUNK - 1)) == 0 && t + CHUNK < TSEQ) {
            const int tb = t + CHUNK;
            {
                int s = tid / 30, r2 = tid % 30, b = r2 / 15, kk = r2 % 15;
                stg0 = xb[(size_t)b * TSEQ * DIN + (size_t)(tb + s) * DIN + kk];
            }
            if (tid + NT < CHUNK * BT * DIN) {
                int i2 = tid + NT;
                int s = i2 / 30, r2 = i2 % 30, b = r2 / 15, kk = r2 % 15;
                stg1 = xb[(size_t)b * TSEQ * DIN + (size_t)(tb + s) * DIN + kk];
            }
        }
        // stage write: 8 iterations later, vmcnt long drained
        if ((t & (CHUNK - 1)) == 8 && t + 8 < TSEQ) {
            const int cb = ((t >> 4) + 1) & 1;
            {
                int s = tid / 30, r2 = tid % 30, b = r2 / 15, kk = r2 % 15;
                sx[cb][s][b][kk] = (f16)stg0;
            }
            if (tid + NT < CHUNK * BT * DIN) {
                int i2 = tid + NT;
                int s = i2 / 30, r2 = i2 % 30, b = r2 / 15, kk = r2 % 15;
                sx[cb][s][b][kk] = (f16)stg1;
            }
        }

        // ---- A-fragments (h0 half shared between both layers) ----
        const int bxf = (t >> 4) & 1;
        const int ts  = t & (CHUNK - 1);
        f16x4 ax = *(const f16x4*)&sx[bxf][ts][m16][4 * lg];
        const char* hb = (const char*)&sh[pr][0][0];
        f16x8 a0 = *(const f16x8*)(hb + ((rb +       16 * lg) ^ szw));  // h0 k 0..31
        f16x8 a1 = *(const f16x8*)(hb + ((rb +  64 + 16 * lg) ^ szw));  // h0 k 32..63
        f16x8 e2 = *(const f16x8*)(hb + ((rb + 128 + 16 * lg) ^ szw));  // h1 k 0..31
        f16x8 e3 = *(const f16x8*)(hb + ((rb + 192 + 16 * lg) ^ szw));  // h1 k 32..63

        // ---- both layers' MFMAs (8 independent chains, interleaved) ----
        f32x4 acc[4], bcc[4];
        #pragma unroll
        for (int i = 0; i < 4; ++i) {
            acc[i] = (f32x4){pb0[i], pb0[i], pb0[i], pb0[i]};
            acc[i] = __builtin_amdgcn_mfma_f32_16x16x16f16(ax, bx[i], acc[i], 0, 0, 0);
            acc[i] = __builtin_amdgcn_mfma_f32_16x16x32_f16(a0, bh0[i][0], acc[i], 0, 0, 0);
            acc[i] = __builtin_amdgcn_mfma_f32_16x16x32_f16(a1, bh0[i][1], acc[i], 0, 0, 0);
            bcc[i] = (f32x4){pb1[i], pb1[i], pb1[i], pb1[i]};
            bcc[i] = __builtin_amdgcn_mfma_f32_16x16x32_f16(a0, bh1[i][0], bcc[i], 0, 0, 0);
            bcc[i] = __builtin_amdgcn_mfma_f32_16x16x32_f16(a1, bh1[i][1], bcc[i], 0, 0, 0);
            bcc[i] = __builtin_amdgcn_mfma_f32_16x16x32_f16(e2, bh1[i][2], bcc[i], 0, 0, 0);
            bcc[i] = __builtin_amdgcn_mfma_f32_16x16x32_f16(e3, bh1[i][3], bcc[i], 0, 0, 0);
        }

        // ---- activations: c0/h0 for t=k+1, c1/h1 for t=k ----
        // (k = TSEQ-1 computes a dummy layer0 from stale-but-finite x; its h0
        //  write and c0 update are never consumed.)
        char* hw = (char*)&sh[pw][0][0];
        #pragma unroll
        for (int r = 0; r < 2; ++r) {
            float i0 = sig_f (acc[0][r]);
            float f0 = sig_f (acc[1][r]);
            float g0 = tanh_f(acc[2][r]);
            float o0 = sig_f (acc[3][r]);
            c0r[r] = f0 * c0r[r] + i0 * g0;
            float h0v = o0 * tanh_f(c0r[r]);

            float i1 = sig_f (bcc[0][r]);
            float f1 = sig_f (bcc[1][r]);
            float g1 = tanh_f(bcc[2][r]);
            float o1 = sig_f (bcc[3][r]);
            c1r[r] = f1 * c1r[r] + i1 * g1;
            float h1v = o1 * tanh_f(c1r[r]);

            if (lg == 0) {   // only real batch rows written; ghosts stay 0
                uint cswz = ((uint)r) << 4;
                uint jb   = (uint)(2 * (16 * w + m16));
                *(f16*)(hw + r * 256 + ((jb      ) ^ cswz)) = (f16)h0v;
                *(f16*)(hw + r * 256 + ((jb + 128) ^ cswz)) = (f16)h1v;
            }
        }
    }
    __syncthreads();

    // ---- FC + softmax on final h1 = sh[1] cols 64..127 ---------------------
    float* sl = (float*)&sx[0][0][0][0];
    if (tid < BT * NCLS) {
        int b = tid >> 2, c = tid & 3;
        const char* h1b = (const char*)&sh[1][0][0];
        float acc = fcb[c];
        for (int j = 0; j < HID; ++j) {
            uint off = (uint)(b * 256) + (((uint)(128 + 2 * j)) ^ (((uint)(b & 7)) << 4));
            acc += (float)(*(const f16*)(h1b + off)) * fcw[c * HID + j];
        }
        sl[tid] = acc;
    }
    __syncthreads();
    if (tid < BT) {
        float l0 = sl[tid * 4 + 0], l1 = sl[tid * 4 + 1];
        float l2 = sl[tid * 4 + 2], l3 = sl[tid * 4 + 3];
        float m = fmaxf(fmaxf(l0, l1), fmaxf(l2, l3));
        float e0 = __expf(l0 - m), e1 = __expf(l1 - m);
        float e2 = __expf(l2 - m), e3 = __expf(l3 - m);
        float inv = rcp_f(e0 + e1 + e2 + e3);
        out[(bbase + tid) * NCLS + 0] = e0 * inv;
        out[(bbase + tid) * NCLS + 1] = e1 * inv;
        out[(bbase + tid) * NCLS + 2] = e2 * inv;
        out[(bbase + tid) * NCLS + 3] = e3 * inv;
    }
}

extern "C" void kernel_launch(void* const* d_in, const int* in_sizes, int n_in,
                              void* d_out, int out_size, void* d_ws, size_t ws_size,
                              hipStream_t stream) {
    (void)in_sizes; (void)n_in; (void)out_size; (void)d_ws; (void)ws_size;
    const float* x    = (const float*)d_in[0];
    const float* wih0 = (const float*)d_in[1];
    const float* whh0 = (const float*)d_in[2];
    const float* bih0 = (const float*)d_in[3];
    const float* bhh0 = (const float*)d_in[4];
    const float* wih1 = (const float*)d_in[5];
    const float* whh1 = (const float*)d_in[6];
    const float* bih1 = (const float*)d_in[7];
    const float* bhh1 = (const float*)d_in[8];
    const float* fcw  = (const float*)d_in[9];
    const float* fcb  = (const float*)d_in[10];
    float* out = (float*)d_out;

    lstm2_pipe<<<NBLK, NT, 0, stream>>>(x, wih0, whh0, bih0, bhh0,
                                        wih1, whh1, bih1, bhh1,
                                        fcw, fcb, out);
}

// Round 6
// 1865.568 us; speedup vs baseline: 4.9442x; 1.0964x over previous
//
#include <hip/hip_runtime.h>

typedef _Float16 f16;
typedef _Float16 f16x4 __attribute__((ext_vector_type(4)));
typedef _Float16 f16x8 __attribute__((ext_vector_type(8)));
typedef float    f32x4 __attribute__((ext_vector_type(4)));

#define BATCH 1024
#define TSEQ  2048
#define DIN   15
#define HID   64
#define BT    16             // REAL batch rows per block: full MFMA M-dim used
#define NBLK  (BATCH / BT)   // 64 blocks -> 1 per CU region, zero contention
#define NT    256            // 4 waves, 1 wave/SIMD
#define CHUNK 16             // timesteps of x per staging chunk
#define NCLS  4

#define P2LOG2E 2.88539008177792681472f   // 2*log2(e)

#if __has_builtin(__builtin_amdgcn_exp2f)
#define EXP2(x) __builtin_amdgcn_exp2f(x)
#else
#define EXP2(x) exp2f(x)
#endif

__device__ __forceinline__ float rcp_f(float x) { return __builtin_amdgcn_rcpf(x); }
// weights prescaled: i/f/o rows by -log2e  -> sigmoid(raw) = rcp(1+exp2(z))
//                    g rows by +2*log2e    -> tanh(raw)    = 1-2*rcp(1+exp2(z))
__device__ __forceinline__ float sig2 (float z) { return rcp_f(1.0f + EXP2(z)); }
__device__ __forceinline__ float tanh2(float z) { return 1.0f - 2.0f * rcp_f(1.0f + EXP2(z)); }
__device__ __forceinline__ float tanhc(float c) { return tanh2(P2LOG2E * c); }

__device__ __forceinline__ f16x8 cvt8s(const float* p, float s) {
    float4 lo = ((const float4*)p)[0];
    float4 hi = ((const float4*)p)[1];
    f16x8 r;
    r[0] = (f16)(s * lo.x); r[1] = (f16)(s * lo.y);
    r[2] = (f16)(s * lo.z); r[3] = (f16)(s * lo.w);
    r[4] = (f16)(s * hi.x); r[5] = (f16)(s * hi.y);
    r[6] = (f16)(s * hi.z); r[7] = (f16)(s * hi.w);
    return r;
}

// Pipelined 2-layer LSTM, ONE barrier per timestep, 16 real batch rows/block.
// Iter k computes gates0(t=k+1) from {x(k+1), h0(k)} AND gates1(t=k) from
// {h0(k), h1(k-1)}; both were written in iter k-1 into sh[(k+1)&1][16][128].
// MFMA conventions (validated rounds 3/5):
//   16x16x32 A: lane l holds A[l&15][8*(l>>4)+i]; 16x16x16 A: A[l&15][4*(l>>4)+i]
//   C: lane l holds C[(l>>4)*4+r][l&15]
// Wave w owns N-tiles {w,w+4,w+8,w+12}: i/f/g/o of hidden j=16w+(l&15) in the
// same lane. With BT=16 every C row (b = 4*lg+r) is a REAL batch row -> the
// activation loop r=0..3 does zero ghost work and every lane writes h0/h1.
__global__ __launch_bounds__(NT, 1)
void lstm2_b16(const float* __restrict__ x,
               const float* __restrict__ wih0, const float* __restrict__ whh0,
               const float* __restrict__ bih0, const float* __restrict__ bhh0,
               const float* __restrict__ wih1, const float* __restrict__ whh1,
               const float* __restrict__ bih1, const float* __restrict__ bhh1,
               const float* __restrict__ fcw,  const float* __restrict__ fcb,
               float* __restrict__ out)
{
    const int tid = threadIdx.x;
    const int w   = tid >> 6;
    const int l   = tid & 63;
    const int m16 = l & 15;       // A-row (batch) / B-col (gate) index
    const int lg  = l >> 4;       // k-group / C-row group
    const int bbase = blockIdx.x * BT;

    __shared__ __align__(16) f16 sx[2][CHUNK][16][16];  // 16 KB dbuf x chunks
    __shared__ __align__(16) f16 sh[2][16][128];        //  8 KB dbuf [h0|h1]
    f16* sxf = &sx[0][0][0][0];

    {   // zero LDS once (x pad col 15 stays 0; h(-1) = 0)
        int4 zero = {0, 0, 0, 0};
        int4* z = (int4*)sx;
        #pragma unroll
        for (int i = 0; i < 4; ++i) z[tid + NT * i] = zero;
        int4* zh = (int4*)sh;
        #pragma unroll
        for (int i = 0; i < 2; ++i) zh[tid + NT * i] = zero;
    }

    // ---- step-invariant weight B-fragments, PRESCALED by gate factor -------
    f16x4 bx[4];        // wih0, K=16 (padded from 15 with 0)
    f16x8 bh0[4][2];    // whh0, K=64
    f16x8 bh1[4][4];    // [wih1|whh1] concat, K=128
    float pb0[4], pb1[4];
    #pragma unroll
    for (int i = 0; i < 4; ++i) {
        const float gsc = (i == 2) ? P2LOG2E : -1.44269504088896340736f;
        const int n = 16 * (w + 4 * i) + m16;   // gate row 0..255
        #pragma unroll
        for (int j = 0; j < 4; ++j) {
            int k = 4 * lg + j;
            bx[i][j] = (f16)((k < DIN) ? gsc * wih0[n * DIN + k] : 0.0f);
        }
        #pragma unroll
        for (int f = 0; f < 2; ++f)
            bh0[i][f] = cvt8s(whh0 + n * HID + 32 * f + 8 * lg, gsc);
        #pragma unroll
        for (int f = 0; f < 4; ++f) {
            int k0 = 32 * f + 8 * lg;
            const float* src = (k0 < HID) ? (wih1 + n * HID + k0)
                                          : (whh1 + n * HID + (k0 - HID));
            bh1[i][f] = cvt8s(src, gsc);
        }
        pb0[i] = gsc * (bih0[n] + bhh0[n]);
        pb1[i] = gsc * (bih1[n] + bhh1[n]);
    }

    const float* xb = x + (size_t)bbase * TSEQ * DIN;

    // ---- staging geometry precomputed ONCE (15 elements per thread/chunk) --
    int goff[15], loff[15];
    #pragma unroll
    for (int j = 0; j < 15; ++j) {
        int idx = tid + NT * j;          // 0..3839 = CHUNK*BT*DIN
        int s   = idx / 240;             // timestep within chunk
        int r2  = idx - s * 240;
        int b   = r2 / 15;
        int kk  = r2 - b * 15;
        goff[j] = b * TSEQ * DIN + s * DIN + kk;   // + t_base*DIN at use
        loff[j] = (s * 16 + b) * 16 + kk;          // f16 index within one buf
    }

    // ---- prologue staging: chunks 0 and 1 ----------------------------------
    #pragma unroll
    for (int j = 0; j < 15; ++j) {
        sxf[loff[j]]        = (f16)xb[goff[j]];
        sxf[4096 + loff[j]] = (f16)xb[goff[j] + CHUNK * DIN];
    }

    float c0r[4] = {0.f, 0.f, 0.f, 0.f};
    float c1r[4] = {0.f, 0.f, 0.f, 0.f};
    float stg[15];

    const uint rb  = (uint)(m16 * 256);        // A-frag row base (bytes)
    const uint szw = ((uint)(m16 & 7)) << 4;   // XOR bank swizzle
    const uint jb  = (uint)(2 * (16 * w + m16));

    __syncthreads();   // zero-init + prologue staging visible

    // ---- prologue compute: h0(0) from x(0), h(-1)=0, c(-1)=0 ---------------
    {
        f16x4 ax = *(const f16x4*)(sxf + ((0 * 16 + m16) << 4) + 4 * lg);
        f32x4 acc[4];
        #pragma unroll
        for (int i = 0; i < 4; ++i) {
            acc[i] = (f32x4){pb0[i], pb0[i], pb0[i], pb0[i]};
            acc[i] = __builtin_amdgcn_mfma_f32_16x16x16f16(ax, bx[i], acc[i], 0, 0, 0);
        }
        char* hw = (char*)&sh[1][0][0];   // iter 0 reads buf 1
        #pragma unroll
        for (int r = 0; r < 4; ++r) {
            float i0 = sig2 (acc[0][r]);
            float g0 = tanh2(acc[2][r]);
            float o0 = sig2 (acc[3][r]);
            c0r[r] = i0 * g0;
            float h0v = o0 * tanhc(c0r[r]);
            int   b   = 4 * lg + r;
            uint  bsw = ((uint)(b & 7)) << 4;
            *(f16*)(hw + b * 256 + (jb ^ bsw)) = (f16)h0v;
        }
    }

    // ---- main loop: iter k -> gates0(k+1) + gates1(k), ONE barrier ---------
    for (int k = 0; k < TSEQ; ++k) {
        __syncthreads();   // sh[pr] (h0(k), h1(k-1)) + staged x visible
        const int t  = k + 1;
        const int pr = t & 1;
        const int pw = k & 1;
        const int ts = t & (CHUNK - 1);

        // T14 staging split: issue loads at ts==0, LDS-write 8 iters later.
        // (t > CHUNK guard: no write before the first load -- round-5 bug fix)
        if (ts == 0 && t + CHUNK < TSEQ) {
            const int ga = (t + CHUNK) * DIN;
            #pragma unroll
            for (int j = 0; j < 15; ++j) stg[j] = xb[goff[j] + ga];
        }
        if (ts == 8 && t > CHUNK && t + 8 < TSEQ) {
            f16* dst = sxf + ((((t >> 4) + 1) & 1) << 12);
            #pragma unroll
            for (int j = 0; j < 15; ++j) dst[loff[j]] = (f16)stg[j];
        }

        // ---- A-fragments (h0 half shared between both layers) ----
        const int bxf = (t >> 4) & 1;
        f16x4 ax = *(const f16x4*)(sxf + (bxf << 12) + ((ts * 16 + m16) << 4) + 4 * lg);
        const char* hb = (const char*)&sh[pr][0][0];
        f16x8 a0 = *(const f16x8*)(hb + ((rb +       16 * lg) ^ szw));  // h0 k 0..31
        f16x8 a1 = *(const f16x8*)(hb + ((rb +  64 + 16 * lg) ^ szw));  // h0 k 32..63
        f16x8 e2 = *(const f16x8*)(hb + ((rb + 128 + 16 * lg) ^ szw));  // h1 k 0..31
        f16x8 e3 = *(const f16x8*)(hb + ((rb + 192 + 16 * lg) ^ szw));  // h1 k 32..63

        // ---- both layers' MFMAs (8 independent chains) ----
        f32x4 acc[4], bcc[4];
        #pragma unroll
        for (int i = 0; i < 4; ++i) {
            acc[i] = (f32x4){pb0[i], pb0[i], pb0[i], pb0[i]};
            acc[i] = __builtin_amdgcn_mfma_f32_16x16x16f16(ax, bx[i], acc[i], 0, 0, 0);
            acc[i] = __builtin_amdgcn_mfma_f32_16x16x32_f16(a0, bh0[i][0], acc[i], 0, 0, 0);
            acc[i] = __builtin_amdgcn_mfma_f32_16x16x32_f16(a1, bh0[i][1], acc[i], 0, 0, 0);
            bcc[i] = (f32x4){pb1[i], pb1[i], pb1[i], pb1[i]};
            bcc[i] = __builtin_amdgcn_mfma_f32_16x16x32_f16(a0, bh1[i][0], bcc[i], 0, 0, 0);
            bcc[i] = __builtin_amdgcn_mfma_f32_16x16x32_f16(a1, bh1[i][1], bcc[i], 0, 0, 0);
            bcc[i] = __builtin_amdgcn_mfma_f32_16x16x32_f16(e2, bh1[i][2], bcc[i], 0, 0, 0);
            bcc[i] = __builtin_amdgcn_mfma_f32_16x16x32_f16(e3, bh1[i][3], bcc[i], 0, 0, 0);
        }

        // ---- activations: ALL 16 C-rows are real batch rows ----
        // (k = TSEQ-1 computes a dummy layer0 from stale-but-finite x; its
        //  h0 write and c0 update are never consumed.)
        char* hw = (char*)&sh[pw][0][0];
        #pragma unroll
        for (int r = 0; r < 4; ++r) {
            float i0 = sig2 (acc[0][r]);
            float f0 = sig2 (acc[1][r]);
            float g0 = tanh2(acc[2][r]);
            float o0 = sig2 (acc[3][r]);
            c0r[r] = f0 * c0r[r] + i0 * g0;
            float h0v = o0 * tanhc(c0r[r]);

            float i1 = sig2 (bcc[0][r]);
            float f1 = sig2 (bcc[1][r]);
            float g1 = tanh2(bcc[2][r]);
            float o1 = sig2 (bcc[3][r]);
            c1r[r] = f1 * c1r[r] + i1 * g1;
            float h1v = o1 * tanhc(c1r[r]);

            int  b   = 4 * lg + r;
            uint bsw = ((uint)(b & 7)) << 4;
            *(f16*)(hw + b * 256 + ((jb      ) ^ bsw)) = (f16)h0v;
            *(f16*)(hw + b * 256 + ((jb + 128) ^ bsw)) = (f16)h1v;
        }
    }
    __syncthreads();

    // ---- FC + softmax on final h1 = sh[1] cols 64..127 ---------------------
    // 64 lanes of wave 0: lane = 4*b + c  ->  one (batch row, class) pair.
    if (tid < 64) {
        const int b = tid >> 2, c = tid & 3;
        const char* h1b = (const char*)&sh[1][0][0];
        float acc = fcb[c];
        #pragma unroll
        for (int j = 0; j < HID; ++j) {
            uint off = (uint)(b * 256) + (((uint)(128 + 2 * j)) ^ (((uint)(b & 7)) << 4));
            acc += (float)(*(const f16*)(h1b + off)) * fcw[c * HID + j];
        }
        float m = fmaxf(acc, __shfl_xor(acc, 1));
        m = fmaxf(m, __shfl_xor(m, 2));
        float e = __expf(acc - m);
        float s = e + __shfl_xor(e, 1);
        s += __shfl_xor(s, 2);
        out[(bbase + b) * NCLS + c] = e * rcp_f(s);
    }
}

extern "C" void kernel_launch(void* const* d_in, const int* in_sizes, int n_in,
                              void* d_out, int out_size, void* d_ws, size_t ws_size,
                              hipStream_t stream) {
    (void)in_sizes; (void)n_in; (void)out_size; (void)d_ws; (void)ws_size;
    const float* x    = (const float*)d_in[0];
    const float* wih0 = (const float*)d_in[1];
    const float* whh0 = (const float*)d_in[2];
    const float* bih0 = (const float*)d_in[3];
    const float* bhh0 = (const float*)d_in[4];
    const float* wih1 = (const float*)d_in[5];
    const float* whh1 = (const float*)d_in[6];
    const float* bih1 = (const float*)d_in[7];
    const float* bhh1 = (const float*)d_in[8];
    const float* fcw  = (const float*)d_in[9];
    const float* fcb  = (const float*)d_in[10];
    float* out = (float*)d_out;

    lstm2_b16<<<NBLK, NT, 0, stream>>>(x, wih0, whh0, bih0, bhh0,
                                       wih1, whh1, bih1, bhh1,
                                       fcw, fcb, out);
}

// Round 7
// 1549.059 us; speedup vs baseline: 5.9544x; 1.2043x over previous
//
#include <hip/hip_runtime.h>

typedef _Float16 f16;
typedef _Float16 f16x4 __attribute__((ext_vector_type(4)));
typedef _Float16 f16x8 __attribute__((ext_vector_type(8)));
typedef float    f32x4 __attribute__((ext_vector_type(4)));

#define BATCH 1024
#define TSEQ  2048
#define DIN   15
#define HID   64
#define BT    4              // real batch rows per block
#define NBLK  (BATCH / BT)   // 256 blocks -> every CU busy
#define NT    256            // 4 waves, 1 wave/SIMD
#define CHUNK 16             // timesteps of x per staging chunk
#define NCLS  4

#define P2LOG2E 2.88539008177792681472f   // 2*log2(e)
#define NLOG2E  -1.44269504088896340736f  // -log2(e)

#if __has_builtin(__builtin_amdgcn_exp2f)
#define EXP2(x) __builtin_amdgcn_exp2f(x)
#else
#define EXP2(x) exp2f(x)
#endif

__device__ __forceinline__ float rcp_f(float x) { return __builtin_amdgcn_rcpf(x); }
// weights prescaled: i/f/o rows by -log2e -> sigmoid(raw) = rcp(1+exp2(z))
//                    g rows by +2*log2e   -> tanh(raw)    = 1-2*rcp(1+exp2(z))
__device__ __forceinline__ float sig2 (float z) { return rcp_f(1.0f + EXP2(z)); }
__device__ __forceinline__ float tanh2(float z) { return 1.0f - 2.0f * rcp_f(1.0f + EXP2(z)); }
__device__ __forceinline__ float tanhc(float c) { return tanh2(P2LOG2E * c); }

__device__ __forceinline__ f16x8 cvt8s(const float* p, float s) {
    float4 lo = ((const float4*)p)[0];
    float4 hi = ((const float4*)p)[1];
    f16x8 r;
    r[0] = (f16)(s * lo.x); r[1] = (f16)(s * lo.y);
    r[2] = (f16)(s * lo.z); r[3] = (f16)(s * lo.w);
    r[4] = (f16)(s * hi.x); r[5] = (f16)(s * hi.y);
    r[6] = (f16)(s * hi.z); r[7] = (f16)(s * hi.w);
    return r;
}

// Two-phase pipelined 2-layer LSTM, BT=4 batch rows/block, 256 blocks.
// Iter k: phase A computes raw gates0(k+1) {x(k+1),h0(k)} and gates1(k)
// {h0(k),h1(k-1)} via MFMA and deposits REAL rows (b<4, f32x4 batch-quad from
// the C-fragment of lg==0 lanes) into gbuf; phase B redistributes: thread
// (l,b,j) activates 2 cells (j, j+32) with register c-state and writes h to
// the swizzled sh tile. This spreads the transcendental work (the round-6
// bottleneck) over 4x more CUs: 20 exp2/rcp per thread-step instead of 80.
// MFMA conventions (validated r3/5/6):
//   16x16x32 A: lane l holds A[l&15][8*(l>>4)+i]; 16x16x16: A[l&15][4*(l>>4)+i]
//   C: lane l holds C[(l>>4)*4+r][l&15]  -> lg==0 rows 0..3 = the real batch.
__global__ __launch_bounds__(NT, 1)
void lstm2_rd(const float* __restrict__ x,
              const float* __restrict__ wih0, const float* __restrict__ whh0,
              const float* __restrict__ bih0, const float* __restrict__ bhh0,
              const float* __restrict__ wih1, const float* __restrict__ whh1,
              const float* __restrict__ bih1, const float* __restrict__ bhh1,
              const float* __restrict__ fcw,  const float* __restrict__ fcb,
              float* __restrict__ out)
{
    const int tid = threadIdx.x;
    const int w   = tid >> 6;
    const int l   = tid & 63;
    const int m16 = l & 15;       // A-row (batch) / B-col (gate) index
    const int lg  = l >> 4;       // k-group / C-row group
    const int bbase = blockIdx.x * BT;

    __shared__ __align__(16) f16   sx[2][CHUNK][16][16];  // 16 KB dbuf x
    __shared__ __align__(16) f16   sh[2][16][128];        //  8 KB dbuf [h0|h1]
    __shared__ __align__(16) float gbuf[2][256][4];       //  8 KB raw gates
    f16* sxf = &sx[0][0][0][0];

    {   // zero LDS once (ghost batch rows stay 0 forever; h(-1)=0)
        int4 zero = {0, 0, 0, 0};
        int4* z = (int4*)sx;
        #pragma unroll
        for (int i = 0; i < 4; ++i) z[tid + NT * i] = zero;
        int4* zh = (int4*)sh;
        #pragma unroll
        for (int i = 0; i < 2; ++i) zh[tid + NT * i] = zero;
    }

    // ---- step-invariant weight B-fragments, PRESCALED by gate factor -------
    f16x4 bx[4];        // wih0, K=16 (padded from 15 with 0)
    f16x8 bh0[4][2];    // whh0, K=64
    f16x8 bh1[4][4];    // [wih1|whh1] concat, K=128
    float pb0[4], pb1[4];
    #pragma unroll
    for (int i = 0; i < 4; ++i) {
        const float gsc = (i == 2) ? P2LOG2E : NLOG2E;
        const int n = 16 * (w + 4 * i) + m16;   // gate row 0..255
        #pragma unroll
        for (int j = 0; j < 4; ++j) {
            int k = 4 * lg + j;
            bx[i][j] = (f16)((k < DIN) ? gsc * wih0[n * DIN + k] : 0.0f);
        }
        #pragma unroll
        for (int f = 0; f < 2; ++f)
            bh0[i][f] = cvt8s(whh0 + n * HID + 32 * f + 8 * lg, gsc);
        #pragma unroll
        for (int f = 0; f < 4; ++f) {
            int k0 = 32 * f + 8 * lg;
            const float* src = (k0 < HID) ? (wih1 + n * HID + k0)
                                          : (whh1 + n * HID + (k0 - HID));
            bh1[i][f] = cvt8s(src, gsc);
        }
        pb0[i] = gsc * (bih0[n] + bhh0[n]);
        pb1[i] = gsc * (bih1[n] + bhh1[n]);
    }

    const float* xb = x + (size_t)bbase * TSEQ * DIN;

    // ---- staging geometry (CHUNK*BT*DIN = 960 elems; <=4 per thread) -------
    int goff[4], loff[4];
    #pragma unroll
    for (int j = 0; j < 4; ++j) {
        int idx = tid + NT * j;          // 0..1023; valid < 960
        int s   = idx / 60;              // timestep within chunk
        int r2  = idx - s * 60;
        int b   = r2 / 15;
        int kk  = r2 - b * 15;
        goff[j] = b * TSEQ * DIN + s * DIN + kk;   // + t_base*DIN at use
        loff[j] = (s * 16 + b) * 16 + kk;          // f16 index within one buf
    }
    const bool v3 = (tid < 960 - 3 * NT);          // j==3 validity

    // ---- prologue staging: chunks 0 and 1 ----------------------------------
    #pragma unroll
    for (int j = 0; j < 4; ++j) {
        if (j < 3 || v3) {
            sxf[loff[j]]        = (f16)xb[goff[j]];
            sxf[4096 + loff[j]] = (f16)xb[goff[j] + CHUNK * DIN];
        }
    }

    // ---- phase-B persistent identity & c-state ------------------------------
    const int pl = tid & 1;          // layer
    const int pb = (tid >> 1) & 3;   // batch row
    const int pj = tid >> 3;         // hidden 0..31 (cells pj and pj+32)
    float cst[2] = {0.0f, 0.0f};
    float stg[4];

    const uint rb  = (uint)(m16 * 256);        // A-frag row base (bytes)
    const uint szw = ((uint)(m16 & 7)) << 4;   // XOR bank swizzle
    const uint wsw = ((uint)pb) << 4;          // write-side swizzle (pb<4)

    __syncthreads();   // zero-init + prologue staging visible

    // ---- prologue A: raw gates0(0) from x(0) (h(-1)=0) ----------------------
    {
        f16x4 ax = *(const f16x4*)(sxf + (m16 << 4) + 4 * lg);
        f32x4 acc[4];
        #pragma unroll
        for (int i = 0; i < 4; ++i) {
            acc[i] = (f32x4){pb0[i], pb0[i], pb0[i], pb0[i]};
            acc[i] = __builtin_amdgcn_mfma_f32_16x16x16f16(ax, bx[i], acc[i], 0, 0, 0);
        }
        if (lg == 0) {
            #pragma unroll
            for (int i = 0; i < 4; ++i)
                *(f32x4*)&gbuf[0][16 * (w + 4 * i) + m16][0] = acc[i];
        }
    }
    __syncthreads();
    // ---- prologue B: h0(0) = act(gates0(0)), c0(0) = i*g --------------------
    if (pl == 0) {
        char* hw = (char*)&sh[1][0][0];   // iter 0 reads sh[1]
        #pragma unroll
        for (int q = 0; q < 2; ++q) {
            int jj = pj + 32 * q;
            float i0 = sig2 (gbuf[0][      jj][pb]);
            float g0 = tanh2(gbuf[0][128 + jj][pb]);
            float o0 = sig2 (gbuf[0][192 + jj][pb]);
            cst[q] = i0 * g0;
            float hv = o0 * tanhc(cst[q]);
            *(f16*)(hw + pb * 256 + (((uint)(2 * jj)) ^ wsw)) = (f16)hv;
        }
    }
    __syncthreads();

    // ---- main loop: 2 barriers/step ----------------------------------------
    for (int k = 0; k < TSEQ; ++k) {
        const int t  = k + 1;
        const int pr = t & 1;
        const int pw = k & 1;
        const int ts = t & (CHUNK - 1);

        // T14 staging: issue loads at ts==0, LDS-write 8 iters later
        if (ts == 0 && t + CHUNK < TSEQ) {
            const int ga = (t + CHUNK) * DIN;
            #pragma unroll
            for (int j = 0; j < 4; ++j)
                if (j < 3 || v3) stg[j] = xb[goff[j] + ga];
        }
        if (ts == 8 && t > CHUNK && t + 8 < TSEQ) {
            f16* dst = sxf + ((((t >> 4) + 1) & 1) << 12);
            #pragma unroll
            for (int j = 0; j < 4; ++j)
                if (j < 3 || v3) dst[loff[j]] = (f16)stg[j];
        }

        // ---- phase A: MFMA both layers, deposit raw gates ----
        const int bxf = (t >> 4) & 1;
        f16x4 ax = *(const f16x4*)(sxf + (bxf << 12) + ((ts * 16 + m16) << 4) + 4 * lg);
        const char* hb = (const char*)&sh[pr][0][0];
        f16x8 a0 = *(const f16x8*)(hb + ((rb +       16 * lg) ^ szw));  // h0 0..31
        f16x8 a1 = *(const f16x8*)(hb + ((rb +  64 + 16 * lg) ^ szw));  // h0 32..63
        f16x8 e2 = *(const f16x8*)(hb + ((rb + 128 + 16 * lg) ^ szw));  // h1 0..31
        f16x8 e3 = *(const f16x8*)(hb + ((rb + 192 + 16 * lg) ^ szw));  // h1 32..63

        f32x4 acc[4], bcc[4];
        #pragma unroll
        for (int i = 0; i < 4; ++i) {
            acc[i] = (f32x4){pb0[i], pb0[i], pb0[i], pb0[i]};
            acc[i] = __builtin_amdgcn_mfma_f32_16x16x16f16(ax, bx[i], acc[i], 0, 0, 0);
            acc[i] = __builtin_amdgcn_mfma_f32_16x16x32_f16(a0, bh0[i][0], acc[i], 0, 0, 0);
            acc[i] = __builtin_amdgcn_mfma_f32_16x16x32_f16(a1, bh0[i][1], acc[i], 0, 0, 0);
            bcc[i] = (f32x4){pb1[i], pb1[i], pb1[i], pb1[i]};
            bcc[i] = __builtin_amdgcn_mfma_f32_16x16x32_f16(a0, bh1[i][0], bcc[i], 0, 0, 0);
            bcc[i] = __builtin_amdgcn_mfma_f32_16x16x32_f16(a1, bh1[i][1], bcc[i], 0, 0, 0);
            bcc[i] = __builtin_amdgcn_mfma_f32_16x16x32_f16(e2, bh1[i][2], bcc[i], 0, 0, 0);
            bcc[i] = __builtin_amdgcn_mfma_f32_16x16x32_f16(e3, bh1[i][3], bcc[i], 0, 0, 0);
        }
        if (lg == 0) {   // C rows 0..3 = the 4 real batch rows, contiguous
            #pragma unroll
            for (int i = 0; i < 4; ++i) {
                const int n = 16 * (w + 4 * i) + m16;
                *(f32x4*)&gbuf[0][n][0] = acc[i];
                *(f32x4*)&gbuf[1][n][0] = bcc[i];
            }
        }
        __syncthreads();   // gbuf visible

        // ---- phase B: redistributed activation, 2 cells/thread ----
        // (k = TSEQ-1: layer-0 cells are garbage-but-finite; never consumed.)
        char* hw = (char*)&sh[pw][0][0];
        #pragma unroll
        for (int q = 0; q < 2; ++q) {
            int jj = pj + 32 * q;
            float gi = gbuf[pl][      jj][pb];
            float gf = gbuf[pl][ 64 + jj][pb];
            float gg = gbuf[pl][128 + jj][pb];
            float go = gbuf[pl][192 + jj][pb];
            float iv = sig2(gi), fv = sig2(gf), gv = tanh2(gg), ov = sig2(go);
            cst[q] = fv * cst[q] + iv * gv;
            float hv = ov * tanhc(cst[q]);
            *(f16*)(hw + pb * 256 + (((uint)(2 * (pl * 64 + jj))) ^ wsw)) = (f16)hv;
        }
        __syncthreads();   // sh[pw] visible; gbuf free for next phase A
    }

    // ---- FC + softmax on final h1 = sh[1] cols 64..127 ---------------------
    if (tid < BT * NCLS) {
        const int b = tid >> 2, c = tid & 3;
        const char* h1b = (const char*)&sh[1][0][0];
        float acc = fcb[c];
        #pragma unroll
        for (int j = 0; j < HID; ++j) {
            uint off = (uint)(b * 256) + (((uint)(128 + 2 * j)) ^ (((uint)b) << 4));
            acc += (float)(*(const f16*)(h1b + off)) * fcw[c * HID + j];
        }
        float m = fmaxf(acc, __shfl_xor(acc, 1));
        m = fmaxf(m, __shfl_xor(m, 2));
        float e = __expf(acc - m);
        float s = e + __shfl_xor(e, 1);
        s += __shfl_xor(s, 2);
        out[(bbase + b) * NCLS + c] = e * rcp_f(s);
    }
}

extern "C" void kernel_launch(void* const* d_in, const int* in_sizes, int n_in,
                              void* d_out, int out_size, void* d_ws, size_t ws_size,
                              hipStream_t stream) {
    (void)in_sizes; (void)n_in; (void)out_size; (void)d_ws; (void)ws_size;
    const float* x    = (const float*)d_in[0];
    const float* wih0 = (const float*)d_in[1];
    const float* whh0 = (const float*)d_in[2];
    const float* bih0 = (const float*)d_in[3];
    const float* bhh0 = (const float*)d_in[4];
    const float* wih1 = (const float*)d_in[5];
    const float* whh1 = (const float*)d_in[6];
    const float* bih1 = (const float*)d_in[7];
    const float* bhh1 = (const float*)d_in[8];
    const float* fcw  = (const float*)d_in[9];
    const float* fcb  = (const float*)d_in[10];
    float* out = (float*)d_out;

    lstm2_rd<<<NBLK, NT, 0, stream>>>(x, wih0, whh0, bih0, bhh0,
                                      wih1, whh1, bih1, bhh1,
                                      fcw, fcb, out);
}